// Round 10
// baseline (118.933 us; speedup 1.0000x reference)
//
#include <hip/hip_runtime.h>
#include <hip/hip_fp16.h>

// Per-point expert-indexed MLP: h = LeakyReLU(h @ W[idx] + b[idx]) x3.
//
// Pipeline (4 dispatches):
//   k_hist    : 1024 pts/block histogram (int4 loads), partials [e][b];
//               EXTRA 71 blocks convert all weights fp32->fp16 into ws
//               (one b128 LDS read then yields 8 weights, not 4).
//   k_scan    : 1 block x 1024; wave e scans expert e's <=512 partials
//   k_scatter : deterministic pos = soff[e] + prefix[e][b] + LDS rank;
//               stages only pid (x is LLC-resident, mlp gathers directly).
//   k_mlp     : expert-uniform blocks, fp16 weights in LDS (2.3 KB), fp32
//               biases/activations/accumulation. MPT=4.
//
// VERIFIED MODEL (R7/R8): k_mlp is LDS-pipe bound, ~12 cyc/ds_read_b128.
// fp32 weights: ~300 reads/thread = ~11us. fp16 halves that: ~152 -> ~6us.
// Accuracy: fp16 weight rel err ~5e-4, fp32 accumulate -> |err| ~1e-2 << 0.355.
// SPILL CONTAINMENT (R6): real loop (#pragma unroll 1) for fused L1+L2,
// sched_barrier fences between phases, launch_bounds(256,2). Do not unroll.

#define L_EXP 16
#define IN0   7
#define C0    16
#define C1    32
#define C2    16
#define NEG   0.2f
#define BLK   256
#define MPT   4
#define SEGPAD (BLK * MPT)   // 1024
#define CHUNK  1024          // points per hist/scatter block
#define NBM    512           // max hist/scatter blocks (n <= 524288)

#define NW0 (L_EXP * IN0 * C0)   // 1792
#define NW1 (L_EXP * C0 * C1)    // 8192
#define NW2 (L_EXP * C1 * C2)    // 8192
#define NWTOT (NW0 + NW1 + NW2)  // 18176
#define PREPBLK ((NWTOT + BLK - 1) / BLK)  // 71

// ws layout:
//   int [0..15]            counts per expert (k_scan)
//   int [16..32]           padded seg offsets, [32] = padded total
//   int [64 .. 64+16*NBM)  partial hist -> exclusive block prefixes [e][b]
//   byte 33792             hW0: 1792 halves  (3584 B)
//   byte 37376             hW1: 8192 halves  (16384 B)
//   byte 53760             hW2: 8192 halves  (16384 B)
//   int [18432 .. )        perm: pid per sorted slot (pads: poison, clamped)
#define WS_PART  64
#define WB_W0    33792
#define WB_W1    37376
#define WB_W2    53760
#define WS_PERM  18432

__global__ void k_hist(const int* __restrict__ idx, int n, int nblk,
                       int* __restrict__ ws,
                       const float* __restrict__ W0,
                       const float* __restrict__ W1,
                       const float* __restrict__ W2) {
    int t = threadIdx.x;
    if (blockIdx.x >= nblk) {
        // weight-conversion blocks
        int k = (blockIdx.x - nblk) * BLK + t;
        __half* hW0 = (__half*)((char*)ws + WB_W0);
        __half* hW1 = (__half*)((char*)ws + WB_W1);
        __half* hW2 = (__half*)((char*)ws + WB_W2);
        if (k < NW0) hW0[k] = __float2half(W0[k]);
        else if (k < NW0 + NW1) hW1[k - NW0] = __float2half(W1[k - NW0]);
        else if (k < NWTOT) hW2[k - NW0 - NW1] = __float2half(W2[k - NW0 - NW1]);
        return;
    }
    __shared__ int bins[L_EXP];
    if (t < L_EXP) bins[t] = 0;
    __syncthreads();
    int i4 = blockIdx.x * CHUNK + t * 4;
    if (i4 + 3 < n) {
        int4 v = *reinterpret_cast<const int4*>(idx + i4);
        atomicAdd(&bins[v.x & 15], 1);
        atomicAdd(&bins[v.y & 15], 1);
        atomicAdd(&bins[v.z & 15], 1);
        atomicAdd(&bins[v.w & 15], 1);
    } else {
#pragma unroll
        for (int q = 0; q < 4; ++q)
            if (i4 + q < n) atomicAdd(&bins[idx[i4 + q] & 15], 1);
    }
    __syncthreads();
    if (t < L_EXP) ws[WS_PART + t * NBM + blockIdx.x] = bins[t];
}

__global__ void k_scan(int* __restrict__ ws, int nblk) {
    int t = threadIdx.x;          // 16 waves, wave e = expert e
    int e = t >> 6, l = t & 63;
    int running = 0;
    for (int c = 0; c < nblk; c += 64) {
        int b = c + l;
        int v = (b < nblk) ? ws[WS_PART + e * NBM + b] : 0;
        int s = v;
#pragma unroll
        for (int d = 1; d < 64; d <<= 1) {
            int u = __shfl_up(s, d, 64);
            if (l >= d) s += u;
        }
        if (b < nblk) ws[WS_PART + e * NBM + b] = running + (s - v);  // exclusive
        running += __shfl(s, 63, 64);
    }
    if (l == 0) ws[e] = running;
    __syncthreads();
    if (t == 0) {
        int run = 0;
        for (int q = 0; q < L_EXP; ++q) {
            ws[16 + q] = run;
            run += ((ws[q] + SEGPAD - 1) / SEGPAD) * SEGPAD;
        }
        ws[32] = run;
    }
}

__global__ void k_scatter(const int* __restrict__ idx, int n,
                          int* __restrict__ ws) {
    __shared__ int soff[L_EXP];
    __shared__ int lcount[L_EXP];
    int t = threadIdx.x;
    if (t < L_EXP) {
        soff[t] = ws[16 + t] + ws[WS_PART + t * NBM + blockIdx.x];
        lcount[t] = 0;
    }
    __syncthreads();
    int i4 = blockIdx.x * CHUNK + t * 4;
#pragma unroll
    for (int q = 0; q < 4; ++q) {
        int i = i4 + q;
        if (i < n) {
            int e = idx[i] & 15;
            int r = atomicAdd(&lcount[e], 1);   // LDS only
            ws[WS_PERM + soff[e] + r] = i;
        }
    }
}

__device__ __forceinline__ float leaky(float a) { return fmaxf(a, NEG * a); }

// unpack 8 fp16 (one b128) -> 8 fp32
__device__ __forceinline__ void h8_unpack(float4 v, float* w) {
    const __half2* p = reinterpret_cast<const __half2*>(&v);
    float2 f0 = __half22float2(p[0]);
    float2 f1 = __half22float2(p[1]);
    float2 f2 = __half22float2(p[2]);
    float2 f3 = __half22float2(p[3]);
    w[0] = f0.x; w[1] = f0.y; w[2] = f1.x; w[3] = f1.y;
    w[4] = f2.x; w[5] = f2.y; w[6] = f3.x; w[7] = f3.y;
}

__global__ void __launch_bounds__(BLK, 2) k_mlp(
    const int* __restrict__ meta, const float* __restrict__ x,
    const float* __restrict__ b0, const float* __restrict__ b1,
    const float* __restrict__ b2, float* __restrict__ out) {
    __shared__ __align__(16) __half sW0h[IN0 * C0];   // 224 B
    __shared__ __align__(16) __half sW1h[C0 * C1];    // 1024 B
    __shared__ __align__(16) __half sW2h[C1 * C2];    // 1024 B
    __shared__ __align__(16) float sB0[C0];
    __shared__ __align__(16) float sB1[C1];
    __shared__ __align__(16) float sB2[C2];

    int start = blockIdx.x * SEGPAD;
    if (start >= meta[32]) return;  // uniform

    int e = 0;
    while (start >= meta[16 + e + 1]) ++e;
    e = __builtin_amdgcn_readfirstlane(e);

    int t = threadIdx.x;
    {
        const __half* hW0 = (const __half*)((const char*)meta + WB_W0) + e * (IN0 * C0);
        const __half* hW1 = (const __half*)((const char*)meta + WB_W1) + e * (C0 * C1);
        const __half* hW2 = (const __half*)((const char*)meta + WB_W2) + e * (C1 * C2);
        if (t < IN0 * C0) sW0h[t] = hW0[t];
        // 512 halves = 256 ushort2: one per thread
        reinterpret_cast<ushort2*>(sW1h)[t] = reinterpret_cast<const ushort2*>(hW1)[t];
        reinterpret_cast<ushort2*>(sW2h)[t] = reinterpret_cast<const ushort2*>(hW2)[t];
        if (t >= 128 && t < 128 + C0) sB0[t - 128] = b0[e * C0 + (t - 128)];
        if (t >= 160 && t < 160 + C1) sB1[t - 160] = b1[e * C1 + (t - 160)];
        if (t >= 192 && t < 192 + C2) sB2[t - 192] = b2[e * C2 + (t - 192)];
    }
    __syncthreads();

    int seg = meta[16 + e];
    int cnt = meta[e];
    int j0 = start - seg + t;

    float xv[MPT][IN0];
    int   pid[MPT];
    bool  act[MPT];
#pragma unroll
    for (int m = 0; m < MPT; ++m) {
        int j = j0 + m * BLK;
        act[m] = (j < cnt);
        int p = meta[WS_PERM + seg + j];   // pad slots: poison ->
        pid[m] = act[m] ? p : 0;           // clamp (no divergent flow)
        const float* xp = x + (size_t)pid[m] * IN0;
        float4 a = *reinterpret_cast<const float4*>(xp);
        float4 b = *reinterpret_cast<const float4*>(xp + 3);
        xv[m][0] = a.x; xv[m][1] = a.y; xv[m][2] = a.z; xv[m][3] = a.w;
        xv[m][4] = b.y; xv[m][5] = b.z; xv[m][6] = b.w;
    }
    __builtin_amdgcn_sched_barrier(0);

    // ---- Layer 0: 7 -> 16. Per c: one 16-half row = 2 b128 reads ----
    float h0[MPT][C0];
#pragma unroll
    for (int m = 0; m < MPT; ++m)
#pragma unroll
        for (int o = 0; o < C0; ++o) h0[m][o] = sB0[o];
#pragma unroll
    for (int c = 0; c < IN0; ++c) {
        float w[16];
        h8_unpack(reinterpret_cast<const float4*>(&sW0h[c * C0])[0], w);
        h8_unpack(reinterpret_cast<const float4*>(&sW0h[c * C0])[1], w + 8);
#pragma unroll
        for (int m = 0; m < MPT; ++m)
#pragma unroll
            for (int o = 0; o < C0; ++o) h0[m][o] = fmaf(xv[m][c], w[o], h0[m][o]);
        if (c == 3) __builtin_amdgcn_sched_barrier(0);  // mid-layer fence
    }
#pragma unroll
    for (int m = 0; m < MPT; ++m)
#pragma unroll
        for (int o = 0; o < C0; ++o) h0[m][o] = leaky(h0[m][o]);
    __builtin_amdgcn_sched_barrier(0);

    // ---- Layers 1+2 fused; REAL loop, 8 h1-neurons per chunk ----
    float h2[MPT][C2];
#pragma unroll
    for (int m = 0; m < MPT; ++m)
#pragma unroll
        for (int o = 0; o < C2; ++o) h2[m][o] = sB2[o];
#pragma unroll 1
    for (int ch = 0; ch < C1 / 8; ++ch) {   // h1 neurons ch*8 .. ch*8+7
        float tv[MPT][8];
#pragma unroll
        for (int m = 0; m < MPT; ++m)
#pragma unroll
            for (int o = 0; o < 8; ++o) tv[m][o] = sB1[ch * 8 + o];
#pragma unroll
        for (int c = 0; c < C0; ++c) {
            float w[8];
            h8_unpack(*reinterpret_cast<const float4*>(&sW1h[c * C1 + ch * 8]), w);
#pragma unroll
            for (int m = 0; m < MPT; ++m)
#pragma unroll
                for (int o = 0; o < 8; ++o) tv[m][o] = fmaf(h0[m][c], w[o], tv[m][o]);
        }
#pragma unroll
        for (int m = 0; m < MPT; ++m)
#pragma unroll
            for (int o = 0; o < 8; ++o) tv[m][o] = leaky(tv[m][o]);
        __builtin_amdgcn_sched_barrier(0);
#pragma unroll
        for (int q = 0; q < 8; ++q) {
            int c1 = ch * 8 + q;
            float w[16];
            h8_unpack(reinterpret_cast<const float4*>(&sW2h[c1 * C2])[0], w);
            h8_unpack(reinterpret_cast<const float4*>(&sW2h[c1 * C2])[1], w + 8);
#pragma unroll
            for (int m = 0; m < MPT; ++m)
#pragma unroll
                for (int o = 0; o < C2; ++o) h2[m][o] = fmaf(tv[m][q], w[o], h2[m][o]);
        }
        __builtin_amdgcn_sched_barrier(0);  // fence at chunk boundary
    }

    // ---- predicated stores ----
#pragma unroll
    for (int m = 0; m < MPT; ++m) {
        if (act[m]) {
            float4* outp = reinterpret_cast<float4*>(out + (size_t)pid[m] * C2);
#pragma unroll
            for (int og = 0; og < C2 / 4; ++og) {
                float4 o;
                o.x = leaky(h2[m][og * 4 + 0]);
                o.y = leaky(h2[m][og * 4 + 1]);
                o.z = leaky(h2[m][og * 4 + 2]);
                o.w = leaky(h2[m][og * 4 + 3]);
                outp[og] = o;
            }
        }
    }
}

extern "C" void kernel_launch(void* const* d_in, const int* in_sizes, int n_in,
                              void* d_out, int out_size, void* d_ws, size_t ws_size,
                              hipStream_t stream) {
    const float* x  = (const float*)d_in[0];
    const int*  idx = (const int*)d_in[1];
    const float* W0 = (const float*)d_in[2];
    const float* b0 = (const float*)d_in[3];
    const float* W1 = (const float*)d_in[4];
    const float* b1 = (const float*)d_in[5];
    const float* W2 = (const float*)d_in[6];
    const float* b2 = (const float*)d_in[7];
    float* out = (float*)d_out;

    int n = in_sizes[1];  // N
    int* ws = (int*)d_ws;

    int nblk = (n + CHUNK - 1) / CHUNK;   // <= NBM
    k_hist<<<nblk + PREPBLK, BLK, 0, stream>>>(idx, n, nblk, ws, W0, W1, W2);
    k_scan<<<1, 1024, 0, stream>>>(ws, nblk);
    k_scatter<<<nblk, BLK, 0, stream>>>(idx, n, ws);

    int mblk = (n + L_EXP * (SEGPAD - 1) + SEGPAD - 1) / SEGPAD;
    k_mlp<<<mblk, BLK, 0, stream>>>(ws, x, b0, b1, b2, out);
}

// Round 12
// 117.605 us; speedup vs baseline: 1.0113x; 1.0113x over previous
//
#include <hip/hip_runtime.h>
#include <hip/hip_fp16.h>

// Per-point expert-indexed MLP: h = LeakyReLU(h @ W[idx] + b[idx]) x3.
//
// Pipeline (4 dispatches):
//   k_hist    : 1024 pts/block histogram (int4 loads), partials [e][b];
//               +72 blocks build TRANSPOSED-PACKED fp16 weights in ws:
//               [o][c]-major, c-pairs packed as half2 (dot2 operand layout).
//   k_scan    : 1 block x 1024; wave e scans expert e's <=512 partials
//   k_scatter : deterministic pos = soff[e] + prefix[e][b] + LDS rank;
//               stages only pid (x is LLC-resident, mlp gathers directly).
//   k_mlp     : expert-uniform blocks, fp16 weights in LDS (2.3 KB),
//               v_dot2_f32_f16: 2 MACs/VALU-inst, fp32 accumulate, NO unpack.
//               MPT=4.
//
// R11 fix: cvt_pkrtz returns __fp16x2, fdot2 wants _Float16x2 -> bit_cast.
// MODEL (R7-R10 verified): LDS ~12cyc/ds_read_b128 -> ~5.5us at fp16 bytes;
// R10 lesson: fp32-unpack cvt made VALU the new ~10us ceiling. fdot2 removes
// the unpack AND halves MAC instructions: VALU ~750 inst/pt ~4.5us.
// SPILL CONTAINMENT (R6): real loop (#pragma unroll 1) for fused L1+L2,
// sched_barrier fences between phases, launch_bounds(256,2). Do not unroll.

#define L_EXP 16
#define IN0   7
#define C0    16
#define C1    32
#define C2    16
#define NEG   0.2f
#define BLK   256
#define MPT   4
#define SEGPAD (BLK * MPT)   // 1024
#define CHUNK  1024          // points per hist/scatter block
#define NBM    512           // max hist/scatter blocks (n <= 524288)

// transposed-packed fp16 weight counts (halves)
#define NW0T 2048            // 16 experts x [16 o][8 c-padded]
#define NW1T 8192            // 16 experts x [32 o][16 c]
#define NW2T 8192            // 16 experts x [16 o][32 c]
#define NWT_TOT (NW0T + NW1T + NW2T)       // 18432
#define PREPBLK (NWT_TOT / BLK)            // 72

// ws layout:
//   int [0..15]            counts per expert (k_scan)
//   int [16..32]           padded seg offsets, [32] = padded total
//   int [64 .. 64+16*NBM)  partial hist -> exclusive block prefixes [e][b]
//   byte 33792             hW0t: 2048 halves (4096 B)   [e][o][c0..7 pad]
//   byte 37888             hW1t: 8192 halves (16384 B)  [e][o][c0..15]
//   byte 54272             hW2t: 8192 halves (16384 B)  [e][o][c0..31]
//   int [18432 .. )        perm: pid per sorted slot (pads: poison, clamped)
#define WS_PART  64
#define WB_W0T   33792
#define WB_W1T   37888
#define WB_W2T   54272
#define WS_PERM  18432

typedef _Float16 h2 __attribute__((ext_vector_type(2)));
union F4H { float4 f4; h2 h[4]; };

__device__ __forceinline__ h2 pk(float a, float b) {
    return __builtin_bit_cast(h2, __builtin_amdgcn_cvt_pkrtz(a, b));
}

__global__ void k_hist(const int* __restrict__ idx, int n, int nblk,
                       int* __restrict__ ws,
                       const float* __restrict__ W0,
                       const float* __restrict__ W1,
                       const float* __restrict__ W2) {
    int t = threadIdx.x;
    if (blockIdx.x >= nblk) {
        // build transposed c-pair-packed fp16 weights
        int k = (blockIdx.x - nblk) * BLK + t;
        __half* hW0 = (__half*)((char*)ws + WB_W0T);
        __half* hW1 = (__half*)((char*)ws + WB_W1T);
        __half* hW2 = (__half*)((char*)ws + WB_W2T);
        if (k < NW0T) {
            int e = k >> 7, r = k & 127, o = r >> 3, c = r & 7;
            float v = (c < IN0) ? W0[e * (IN0 * C0) + c * C0 + o] : 0.0f;
            hW0[k] = __float2half(v);
        } else if (k < NW0T + NW1T) {
            int k2 = k - NW0T;
            int e = k2 >> 9, r = k2 & 511, o = r >> 4, c = r & 15;
            hW1[k2] = __float2half(W1[e * (C0 * C1) + c * C1 + o]);
        } else {
            int k2 = k - NW0T - NW1T;
            int e = k2 >> 9, r = k2 & 511, o = r >> 5, c = r & 31;
            hW2[k2] = __float2half(W2[e * (C1 * C2) + c * C2 + o]);
        }
        return;
    }
    __shared__ int bins[L_EXP];
    if (t < L_EXP) bins[t] = 0;
    __syncthreads();
    int i4 = blockIdx.x * CHUNK + t * 4;
    if (i4 + 3 < n) {
        int4 v = *reinterpret_cast<const int4*>(idx + i4);
        atomicAdd(&bins[v.x & 15], 1);
        atomicAdd(&bins[v.y & 15], 1);
        atomicAdd(&bins[v.z & 15], 1);
        atomicAdd(&bins[v.w & 15], 1);
    } else {
#pragma unroll
        for (int q = 0; q < 4; ++q)
            if (i4 + q < n) atomicAdd(&bins[idx[i4 + q] & 15], 1);
    }
    __syncthreads();
    if (t < L_EXP) ws[WS_PART + t * NBM + blockIdx.x] = bins[t];
}

__global__ void k_scan(int* __restrict__ ws, int nblk) {
    int t = threadIdx.x;          // 16 waves, wave e = expert e
    int e = t >> 6, l = t & 63;
    int running = 0;
    for (int c = 0; c < nblk; c += 64) {
        int b = c + l;
        int v = (b < nblk) ? ws[WS_PART + e * NBM + b] : 0;
        int s = v;
#pragma unroll
        for (int d = 1; d < 64; d <<= 1) {
            int u = __shfl_up(s, d, 64);
            if (l >= d) s += u;
        }
        if (b < nblk) ws[WS_PART + e * NBM + b] = running + (s - v);  // exclusive
        running += __shfl(s, 63, 64);
    }
    if (l == 0) ws[e] = running;
    __syncthreads();
    if (t == 0) {
        int run = 0;
        for (int q = 0; q < L_EXP; ++q) {
            ws[16 + q] = run;
            run += ((ws[q] + SEGPAD - 1) / SEGPAD) * SEGPAD;
        }
        ws[32] = run;
    }
}

__global__ void k_scatter(const int* __restrict__ idx, int n,
                          int* __restrict__ ws) {
    __shared__ int soff[L_EXP];
    __shared__ int lcount[L_EXP];
    int t = threadIdx.x;
    if (t < L_EXP) {
        soff[t] = ws[16 + t] + ws[WS_PART + t * NBM + blockIdx.x];
        lcount[t] = 0;
    }
    __syncthreads();
    int i4 = blockIdx.x * CHUNK + t * 4;
#pragma unroll
    for (int q = 0; q < 4; ++q) {
        int i = i4 + q;
        if (i < n) {
            int e = idx[i] & 15;
            int r = atomicAdd(&lcount[e], 1);   // LDS only
            ws[WS_PERM + soff[e] + r] = i;
        }
    }
}

__device__ __forceinline__ float leaky(float a) { return fmaxf(a, NEG * a); }

__device__ __forceinline__ float fdot2(h2 a, h2 b, float c) {
    return __builtin_amdgcn_fdot2(a, b, c, false);
}

__global__ void __launch_bounds__(BLK, 2) k_mlp(
    const int* __restrict__ meta, const float* __restrict__ x,
    const float* __restrict__ b0, const float* __restrict__ b1,
    const float* __restrict__ b2, float* __restrict__ out) {
    __shared__ __align__(16) __half sW0t[C0 * 8];     // [o][c0..7]  256 B
    __shared__ __align__(16) __half sW1t[C1 * C0];    // [o][c0..15] 1 KB
    __shared__ __align__(16) __half sW2t[C2 * C1];    // [o][c0..31] 1 KB
    __shared__ __align__(16) float sB0[C0];
    __shared__ __align__(16) float sB1[C1];
    __shared__ __align__(16) float sB2[C2];

    int start = blockIdx.x * SEGPAD;
    if (start >= meta[32]) return;  // uniform

    int e = 0;
    while (start >= meta[16 + e + 1]) ++e;
    e = __builtin_amdgcn_readfirstlane(e);

    int t = threadIdx.x;
    {
        const int* w0i = (const int*)((const char*)meta + WB_W0T) + e * 64;
        const int* w1i = (const int*)((const char*)meta + WB_W1T) + e * 256;
        const int* w2i = (const int*)((const char*)meta + WB_W2T) + e * 256;
        if (t < 64) reinterpret_cast<int*>(sW0t)[t] = w0i[t];
        reinterpret_cast<int*>(sW1t)[t] = w1i[t];
        reinterpret_cast<int*>(sW2t)[t] = w2i[t];
        if (t >= 128 && t < 128 + C0) sB0[t - 128] = b0[e * C0 + (t - 128)];
        if (t >= 160 && t < 160 + C1) sB1[t - 160] = b1[e * C1 + (t - 160)];
        if (t >= 192 && t < 192 + C2) sB2[t - 192] = b2[e * C2 + (t - 192)];
    }
    __syncthreads();

    int seg = meta[16 + e];
    int cnt = meta[e];
    int j0 = start - seg + t;

    h2  xh[MPT][4];
    int pid[MPT];
    bool act[MPT];
#pragma unroll
    for (int m = 0; m < MPT; ++m) {
        int j = j0 + m * BLK;
        act[m] = (j < cnt);
        int p = meta[WS_PERM + seg + j];   // pad slots: poison ->
        pid[m] = act[m] ? p : 0;           // clamp (no divergent flow)
        const float* xp = x + (size_t)pid[m] * IN0;
        float4 a = *reinterpret_cast<const float4*>(xp);
        float4 b = *reinterpret_cast<const float4*>(xp + 3);
        xh[m][0] = pk(a.x, a.y);
        xh[m][1] = pk(a.z, a.w);
        xh[m][2] = pk(b.y, b.z);
        xh[m][3] = pk(b.w, 0.0f);  // pad c=7 (weight there is 0 too)
    }
    __builtin_amdgcn_sched_barrier(0);

    // ---- Layer 0: 7 -> 16. Per o: one b128 row (4 half2), 4 fdot2/pt ----
    float h0f[MPT][C0];
#pragma unroll
    for (int o = 0; o < C0; ++o) {
        F4H u;
        u.f4 = *reinterpret_cast<const float4*>(&sW0t[o * 8]);
#pragma unroll
        for (int m = 0; m < MPT; ++m) {
            float a = sB0[o];
            a = fdot2(xh[m][0], u.h[0], a);
            a = fdot2(xh[m][1], u.h[1], a);
            a = fdot2(xh[m][2], u.h[2], a);
            a = fdot2(xh[m][3], u.h[3], a);
            h0f[m][o] = leaky(a);
        }
        if (o == 7) __builtin_amdgcn_sched_barrier(0);  // mid-layer fence
    }
    // pack h0 into half2 pairs for layer-1 dot2
    h2 h0h[MPT][8];
#pragma unroll
    for (int m = 0; m < MPT; ++m)
#pragma unroll
        for (int p = 0; p < 8; ++p)
            h0h[m][p] = pk(h0f[m][2 * p], h0f[m][2 * p + 1]);
    __builtin_amdgcn_sched_barrier(0);

    // ---- Layers 1+2 fused; REAL loop, 8 h1-neurons per chunk ----
    float h2a[MPT][C2];
#pragma unroll
    for (int m = 0; m < MPT; ++m)
#pragma unroll
        for (int o = 0; o < C2; ++o) h2a[m][o] = sB2[o];
#pragma unroll 1
    for (int ch = 0; ch < C1 / 8; ++ch) {   // h1 neurons ch*8 .. ch*8+7
        float tvf[MPT][8];
#pragma unroll
        for (int o8 = 0; o8 < 8; ++o8) {
            int o = ch * 8 + o8;
            F4H ua, ub;
            ua.f4 = reinterpret_cast<const float4*>(&sW1t[o * C0])[0];
            ub.f4 = reinterpret_cast<const float4*>(&sW1t[o * C0])[1];
#pragma unroll
            for (int m = 0; m < MPT; ++m) {
                float a = sB1[o];
                a = fdot2(h0h[m][0], ua.h[0], a);
                a = fdot2(h0h[m][1], ua.h[1], a);
                a = fdot2(h0h[m][2], ua.h[2], a);
                a = fdot2(h0h[m][3], ua.h[3], a);
                a = fdot2(h0h[m][4], ub.h[0], a);
                a = fdot2(h0h[m][5], ub.h[1], a);
                a = fdot2(h0h[m][6], ub.h[2], a);
                a = fdot2(h0h[m][7], ub.h[3], a);
                tvf[m][o8] = leaky(a);
            }
        }
        __builtin_amdgcn_sched_barrier(0);
        h2 tvh[MPT][4];
#pragma unroll
        for (int m = 0; m < MPT; ++m)
#pragma unroll
            for (int p = 0; p < 4; ++p)
                tvh[m][p] = pk(tvf[m][2 * p], tvf[m][2 * p + 1]);
#pragma unroll
        for (int o = 0; o < C2; ++o) {
            F4H u;
            u.f4 = *reinterpret_cast<const float4*>(&sW2t[o * C1 + ch * 8]);
#pragma unroll
            for (int m = 0; m < MPT; ++m) {
                float a = h2a[m][o];
                a = fdot2(tvh[m][0], u.h[0], a);
                a = fdot2(tvh[m][1], u.h[1], a);
                a = fdot2(tvh[m][2], u.h[2], a);
                a = fdot2(tvh[m][3], u.h[3], a);
                h2a[m][o] = a;
            }
        }
        __builtin_amdgcn_sched_barrier(0);  // fence at chunk boundary
    }

    // ---- predicated stores ----
#pragma unroll
    for (int m = 0; m < MPT; ++m) {
        if (act[m]) {
            float4* outp = reinterpret_cast<float4*>(out + (size_t)pid[m] * C2);
#pragma unroll
            for (int og = 0; og < C2 / 4; ++og) {
                float4 o;
                o.x = leaky(h2a[m][og * 4 + 0]);
                o.y = leaky(h2a[m][og * 4 + 1]);
                o.z = leaky(h2a[m][og * 4 + 2]);
                o.w = leaky(h2a[m][og * 4 + 3]);
                outp[og] = o;
            }
        }
    }
}

extern "C" void kernel_launch(void* const* d_in, const int* in_sizes, int n_in,
                              void* d_out, int out_size, void* d_ws, size_t ws_size,
                              hipStream_t stream) {
    const float* x  = (const float*)d_in[0];
    const int*  idx = (const int*)d_in[1];
    const float* W0 = (const float*)d_in[2];
    const float* b0 = (const float*)d_in[3];
    const float* W1 = (const float*)d_in[4];
    const float* b1 = (const float*)d_in[5];
    const float* W2 = (const float*)d_in[6];
    const float* b2 = (const float*)d_in[7];
    float* out = (float*)d_out;

    int n = in_sizes[1];  // N
    int* ws = (int*)d_ws;

    int nblk = (n + CHUNK - 1) / CHUNK;   // <= NBM
    k_hist<<<nblk + PREPBLK, BLK, 0, stream>>>(idx, n, nblk, ws, W0, W1, W2);
    k_scan<<<1, 1024, 0, stream>>>(ws, nblk);
    k_scatter<<<nblk, BLK, 0, stream>>>(idx, n, ws);

    int mblk = (n + L_EXP * (SEGPAD - 1) + SEGPAD - 1) / SEGPAD;
    k_mlp<<<mblk, BLK, 0, stream>>>(ws, x, b0, b1, b2, out);
}